// Round 7
// baseline (677.868 us; speedup 1.0000x reference)
//
#include <hip/hip_runtime.h>
#include <hip/hip_bf16.h>
#include <math.h>

#define N_NODES   8192
#define NUM_E     49152
#define NUM_EDGES (NUM_E + N_NODES)   // 57344 (with self loops)
#define H_HEADS   6
#define C_DIM     512
#define HC        (H_HEADS * C_DIM)   // 3072
#define XLR       (2 * HC)            // 6144: xl | xr concatenated per row
#define N_FEAT    37
#define LRELU_SLOPE 0.2f
#define SELU_LAMBDA 1.0507009873554805f
#define SELU_ALPHA  1.6732632423543772f

typedef __bf16 bf16_t;
typedef bf16_t bf16x8 __attribute__((ext_vector_type(8)));
typedef float  f32x4  __attribute__((ext_vector_type(4)));
typedef float  f32x2  __attribute__((ext_vector_type(2)));

__device__ __forceinline__ int edge_src(const int* ei, int e) {
    return e < NUM_E ? ei[e] : (e - NUM_E);
}
__device__ __forceinline__ int edge_dst(const int* ei, int e) {
    return e < NUM_E ? ei[NUM_E + e] : (e - NUM_E);
}
__device__ __forceinline__ float selu_f(float v) {
    return v > 0.f ? SELU_LAMBDA * v : SELU_LAMBDA * SELU_ALPHA * (__expf(v) - 1.f);
}
__device__ __forceinline__ void gload_lds16(const void* g, void* l) {
    __builtin_amdgcn_global_load_lds((const __attribute__((address_space(1))) void*)g,
                                     (__attribute__((address_space(3))) void*)l, 16, 0, 0);
}

// ---------------- K1: hidden0 = selu([x[:,2:],lf,cf] @ W_lin + b) -> bf16, coord init
__global__ __launch_bounds__(512) void k_hidden0(
    const float* __restrict__ x, const float* __restrict__ lf,
    const float* __restrict__ cf, const float* __restrict__ W,
    const float* __restrict__ b, bf16_t* __restrict__ hidden,
    float* __restrict__ coord)
{
    int n = blockIdx.x;
    int c = threadIdx.x;
    __shared__ float f[N_FEAT];
    if (c < 5)            f[c] = x[n*7 + 2 + c];
    else if (c < 21)      f[c] = lf[n*16 + (c-5)];
    else if (c < N_FEAT)  f[c] = cf[n*16 + (c-21)];
    if (c < 2) coord[n*2 + c] = x[n*7 + c];
    __syncthreads();
    float acc = b[c];
    #pragma unroll
    for (int k = 0; k < N_FEAT; ++k) acc = fmaf(f[k], W[k*C_DIM + c], acc);
    hidden[n*C_DIM + c] = (bf16_t)selu_f(acc);
}

// ---------------- weight transpose+convert: W (514x3072 fp32, skip rows 0,1) -> WT (3072x512 bf16)
__global__ __launch_bounds__(256) void k_wt_transpose(const float* __restrict__ W,
                                                      bf16_t* __restrict__ WT)
{
    __shared__ float tile[32][33];
    int k0 = blockIdx.y * 32;
    int n0 = blockIdx.x * 32;
    int tx = threadIdx.x & 31, ty = threadIdx.x >> 5;
    #pragma unroll
    for (int i = 0; i < 4; ++i)
        tile[ty + i*8][tx] = W[(size_t)(k0 + 2 + ty + i*8) * HC + n0 + tx];
    __syncthreads();
    #pragma unroll
    for (int i = 0; i < 4; ++i)
        WT[(size_t)(n0 + ty + i*8) * C_DIM + k0 + tx] = (bf16_t)tile[tx][ty + i*8];
}

// ---------------- CSR build
__global__ void k_hist(const int* __restrict__ ei, int* __restrict__ counts) {
    int e = blockIdx.x * blockDim.x + threadIdx.x;
    if (e >= NUM_EDGES) return;
    atomicAdd(&counts[edge_dst(ei, e)], 1);
}

__global__ __launch_bounds__(256) void k_scan(const int* __restrict__ counts,
                                              int* __restrict__ row_ptr,
                                              int* __restrict__ cursor) {
    __shared__ int part[256];
    __shared__ int off[257];
    int t = threadIdx.x;
    int base = t * 32;
    int local[32];
    int s = 0;
    #pragma unroll
    for (int i = 0; i < 32; ++i) { local[i] = s; s += counts[base + i]; }
    part[t] = s;
    __syncthreads();
    if (t == 0) {
        off[0] = 0;
        for (int i = 0; i < 256; ++i) off[i+1] = off[i] + part[i];
    }
    __syncthreads();
    int o = off[t];
    #pragma unroll
    for (int i = 0; i < 32; ++i) {
        int v = o + local[i];
        row_ptr[base + i] = v;
        cursor[base + i]  = v;
    }
    if (t == 255) row_ptr[N_NODES] = off[256];
}

__global__ void k_scatter(const int* __restrict__ ei, int* __restrict__ cursor,
                          int* __restrict__ csr_eid) {
    int e = blockIdx.x * blockDim.x + threadIdx.x;
    if (e >= NUM_EDGES) return;
    int pos = atomicAdd(&cursor[edge_dst(ei, e)], 1);
    csr_eid[pos] = e;
}

// ---------------- bf16 MFMA GEMM: double-buffered LDS, staging issued BEFORE compute phase
// so the global_load_lds latency overlaps ds_read+MFMA; one barrier per K-iter.
// XOR-swizzled K-chunks keep ds_read_b128 conflict-free.
#define GM 128
#define GN 128
#define GK 32
__global__ __launch_bounds__(256) void k_gemm_bf16(
    const bf16_t* __restrict__ A,
    const bf16_t* __restrict__ BT,
    const float*  __restrict__ Wl,
    const float*  __restrict__ Wr,
    const float*  __restrict__ coord,
    bf16_t* __restrict__ out)
{
    __shared__ bf16_t As[2][GM][GK];   // 16 KB
    __shared__ bf16_t Bs[2][GM][GK];   // 16 KB
    int tid  = threadIdx.x;
    int wave = tid >> 6;
    int lane = tid & 63;
    int rowBase = blockIdx.y * GM;
    int colBase = blockIdx.x * GN;
    int wr = (wave >> 1) * 64;
    int wc = (wave & 1) * 64;

    f32x4 acc[4][4] = {};

    // stager: lane -> row wave*32 + lane/4 (and +16), fetches global chunk (lane&3)^((lane>>3)&3)
    int gsw = (((lane & 3) ^ ((lane >> 3) & 3))) * 8;
    const bf16_t* Ag = A  + (size_t)(rowBase + wave*32 + (lane >> 2)) * C_DIM + gsw;
    const bf16_t* Bg = BT + (size_t)(colBase + wave*32 + (lane >> 2)) * C_DIM + gsw;
    int m16 = lane & 15;
    // reader: wants global chunk lane>>4 at row m16 -> physical chunk (lane>>4)^((lane>>1)&3)
    int q8s = (((lane >> 4) ^ ((lane >> 1) & 3))) * 8;

    // prologue: stage k0=0 into buffer 0
    gload_lds16(Ag,            &As[0][wave*32     ][0]);
    gload_lds16(Ag + 16*C_DIM, &As[0][wave*32 + 16][0]);
    gload_lds16(Bg,            &Bs[0][wave*32     ][0]);
    gload_lds16(Bg + 16*C_DIM, &Bs[0][wave*32 + 16][0]);

    int p = 0;
    for (int k0 = 0; k0 < C_DIM; k0 += GK) {
        __syncthreads();   // staging of buf p complete; prior reads of buf p^1 done
        if (k0 + GK < C_DIM) {
            gload_lds16(Ag + k0 + GK,            &As[p^1][wave*32     ][0]);
            gload_lds16(Ag + k0 + GK + 16*C_DIM, &As[p^1][wave*32 + 16][0]);
            gload_lds16(Bg + k0 + GK,            &Bs[p^1][wave*32     ][0]);
            gload_lds16(Bg + k0 + GK + 16*C_DIM, &Bs[p^1][wave*32 + 16][0]);
        }
        bf16x8 af[4], bfr[4];
        #pragma unroll
        for (int i = 0; i < 4; ++i) af[i]  = *(const bf16x8*)&As[p][wr + i*16 + m16][q8s];
        #pragma unroll
        for (int j = 0; j < 4; ++j) bfr[j] = *(const bf16x8*)&Bs[p][wc + j*16 + m16][q8s];
        #pragma unroll
        for (int i = 0; i < 4; ++i)
            #pragma unroll
            for (int j = 0; j < 4; ++j)
                acc[i][j] = __builtin_amdgcn_mfma_f32_16x16x32_bf16(af[i], bfr[j], acc[i][j], 0, 0, 0);
        p ^= 1;
    }

    const float* Wtop = (colBase < HC) ? Wl : Wr;
    int coff = (colBase < HC) ? 0 : HC;

    int ccol  = lane & 15;
    int crow4 = (lane >> 4) * 4;
    #pragma unroll
    for (int i = 0; i < 4; ++i) {
        #pragma unroll
        for (int r = 0; r < 4; ++r) {
            int row = rowBase + wr + i*16 + crow4 + r;
            float c0 = coord[row*2 + 0], c1 = coord[row*2 + 1];
            size_t rb = (size_t)row * XLR;
            #pragma unroll
            for (int j = 0; j < 4; ++j) {
                int col = colBase + wc + j*16 + ccol;
                int wcol = col - coff;
                out[rb + col] = (bf16_t)(acc[i][j][r] + c0 * Wtop[wcol] + c1 * Wtop[HC + wcol]);
            }
        }
    }
}

// ---------------- fused attention, no-max softmax, 4-edge unrolled (4 gathers in flight)
#define MAX_DEG 128
__global__ __launch_bounds__(384) void k_attn_agg(
    const bf16_t* __restrict__ xlr,
    const int* __restrict__ row_ptr, const int* __restrict__ csr_eid,
    const int* __restrict__ ei, const float* __restrict__ att,
    const float* __restrict__ gat_bias, const float* __restrict__ W_coord,
    const float* __restrict__ b_coord, const float* __restrict__ coord_in,
    bf16_t* __restrict__ hidden, float* __restrict__ coord_out)
{
    int n = blockIdx.x;
    int tid = threadIdx.x;
    int h = tid >> 6, lane = tid & 63;
    __shared__ int   s_src[MAX_DEG];
    __shared__ float s_acc[HC];        // 12 KB
    __shared__ float s_red[12];

    int beg = row_ptr[n];
    int deg = min(row_ptr[n + 1] - beg, MAX_DEG);
    for (int j = tid; j < deg; j += 384) s_src[j] = edge_src(ei, csr_eid[beg + j]);
    __syncthreads();

    size_t off = (size_t)h * C_DIM + lane * 8;
    bf16x8 xrv = *(const bf16x8*)(xlr + (size_t)n * XLR + HC + off);
    f32x2 xr2[4], at2[4], ac2[4] = {};
    #pragma unroll
    for (int i = 0; i < 4; ++i) {
        xr2[i] = f32x2{(float)xrv[2*i], (float)xrv[2*i+1]};
        at2[i] = f32x2{att[off + 2*i], att[off + 2*i + 1]};
    }

    float l = 0.f;
    int j = 0;
    for (; j + 4 <= deg; j += 4) {
        bf16x8 xv[4];
        #pragma unroll
        for (int u = 0; u < 4; ++u)
            xv[u] = *(const bf16x8*)(xlr + (size_t)s_src[j + u] * XLR + off);
        f32x2 xl2[4][4];
        float sum[4];
        #pragma unroll
        for (int u = 0; u < 4; ++u) {
            f32x2 s2 = {0.f, 0.f};
            #pragma unroll
            for (int i = 0; i < 4; ++i) {
                xl2[u][i] = f32x2{(float)xv[u][2*i], (float)xv[u][2*i+1]};
                f32x2 v = xl2[u][i] + xr2[i];
                s2 += __builtin_elementwise_max(v, v * LRELU_SLOPE) * at2[i];
            }
            sum[u] = s2.x + s2.y;
        }
        #pragma unroll
        for (int o = 1; o < 64; o <<= 1) {
            #pragma unroll
            for (int u = 0; u < 4; ++u) sum[u] += __shfl_xor(sum[u], o);
        }
        #pragma unroll
        for (int u = 0; u < 4; ++u) {
            float a = __expf(sum[u]);
            l += a;
            #pragma unroll
            for (int i = 0; i < 4; ++i) ac2[i] += a * xl2[u][i];
        }
    }
    for (; j < deg; ++j) {
        bf16x8 xa = *(const bf16x8*)(xlr + (size_t)s_src[j] * XLR + off);
        f32x2 xla[4];
        #pragma unroll
        for (int i = 0; i < 4; ++i) xla[i] = f32x2{(float)xa[2*i], (float)xa[2*i+1]};
        f32x2 sa = {0.f, 0.f};
        #pragma unroll
        for (int i = 0; i < 4; ++i) {
            f32x2 va = xla[i] + xr2[i];
            sa += __builtin_elementwise_max(va, va * LRELU_SLOPE) * at2[i];
        }
        float suma = sa.x + sa.y;
        #pragma unroll
        for (int o = 1; o < 64; o <<= 1) suma += __shfl_xor(suma, o);
        float aa = __expf(suma);
        l += aa;
        #pragma unroll
        for (int i = 0; i < 4; ++i) ac2[i] += aa * xla[i];
    }

    float invl = 1.f / (l + 1e-16f) * (1.f / 6.f);   // fold head-mean
    #pragma unroll
    for (int i = 0; i < 4; ++i) {
        s_acc[off + 2*i]     = ac2[i].x * invl;
        s_acc[off + 2*i + 1] = ac2[i].y * invl;
    }
    __syncthreads();

    float p0 = 0.f, p1 = 0.f;
    for (int c = tid; c < C_DIM; c += 384) {
        float s = 0.f;
        #pragma unroll
        for (int hh = 0; hh < H_HEADS; ++hh) s += s_acc[hh * C_DIM + c];
        float hv = selu_f(s + gat_bias[c]);
        hidden[n * C_DIM + c] = (bf16_t)hv;
        p0 = fmaf(hv, W_coord[c * 2 + 0], p0);
        p1 = fmaf(hv, W_coord[c * 2 + 1], p1);
    }
    #pragma unroll
    for (int o = 32; o > 0; o >>= 1) { p0 += __shfl_down(p0, o); p1 += __shfl_down(p1, o); }
    if (lane == 0) { s_red[h * 2] = p0; s_red[h * 2 + 1] = p1; }
    __syncthreads();
    if (tid == 0) {
        float o0 = b_coord[0], o1 = b_coord[1];
        #pragma unroll
        for (int w = 0; w < H_HEADS; ++w) { o0 += s_red[w * 2]; o1 += s_red[w * 2 + 1]; }
        float cx = coord_in[n * 2 + 0], cy = coord_in[n * 2 + 1];
        float ox = (cx == 0.0f) ? 0.f : ((cx == 1.0f) ? 1.f : o0);
        float oy = (cy == 1.0f) ? 1.f : ((cy == 0.0f) ? 0.f : o1);
        coord_out[n * 2 + 0] = ox;
        coord_out[n * 2 + 1] = oy;
    }
}

extern "C" void kernel_launch(void* const* d_in, const int* in_sizes, int n_in,
                              void* d_out, int out_size, void* d_ws, size_t ws_size,
                              hipStream_t stream)
{
    const float* x       = (const float*)d_in[0];
    const float* lf      = (const float*)d_in[1];
    const float* cf      = (const float*)d_in[2];
    const float* W_lin   = (const float*)d_in[3];
    const float* b_lin   = (const float*)d_in[4];
    const float* Wl      = (const float*)d_in[5];
    const float* Wr      = (const float*)d_in[6];
    const float* att     = (const float*)d_in[7];
    const float* gbias   = (const float*)d_in[8];
    const float* W_coord = (const float*)d_in[9];
    const float* b_coord = (const float*)d_in[10];
    const int*   ei      = (const int*)d_in[11];

    char* w = (char*)d_ws;
    auto alloc = [&](size_t bytes) { char* p = w; w += (bytes + 255) & ~255ull; return p; };
    bf16_t*   hidden  = (bf16_t*)alloc((size_t)N_NODES * C_DIM * 2);
    bf16_t*   WT      = (bf16_t*)alloc((size_t)XLR * C_DIM * 2);
    bf16_t*   xlr     = (bf16_t*)alloc((size_t)N_NODES * XLR * 2);
    int*      counts  = (int*)alloc((size_t)N_NODES * 4);
    int*      row_ptr = (int*)alloc((size_t)(N_NODES + 1) * 4);
    int*      cursor  = (int*)alloc((size_t)N_NODES * 4);
    int*      csr_eid = (int*)alloc((size_t)NUM_EDGES * 4);
    float*    cA      = (float*)alloc((size_t)N_NODES * 2 * 4);
    float*    cB      = (float*)alloc((size_t)N_NODES * 2 * 4);

    hipMemsetAsync(counts, 0, (size_t)N_NODES * 4, stream);
    k_hidden0<<<N_NODES, 512, 0, stream>>>(x, lf, cf, W_lin, b_lin, hidden, cA);
    {
        dim3 tg(HC / 32, C_DIM / 32);
        k_wt_transpose<<<tg, 256, 0, stream>>>(Wl, WT);
        k_wt_transpose<<<tg, 256, 0, stream>>>(Wr, WT + (size_t)HC * C_DIM);
    }
    k_hist<<<(NUM_EDGES + 255) / 256, 256, 0, stream>>>(ei, counts);
    k_scan<<<1, 256, 0, stream>>>(counts, row_ptr, cursor);
    k_scatter<<<(NUM_EDGES + 255) / 256, 256, 0, stream>>>(ei, cursor, csr_eid);

    float* cin = cA;
    for (int it = 0; it < 3; ++it) {
        float* cout = (it == 2) ? (float*)d_out : ((it == 0) ? cB : cA);
        dim3 g(XLR / GN, N_NODES / GM);
        k_gemm_bf16<<<g, 256, 0, stream>>>(hidden, WT, Wl, Wr, cin, xlr);
        k_attn_agg<<<N_NODES, 384, 0, stream>>>(xlr, row_ptr, csr_eid, ei, att,
                                                gbias, W_coord, b_coord, cin, hidden, cout);
        cin = cout;
    }
}

// Round 8
// 579.680 us; speedup vs baseline: 1.1694x; 1.1694x over previous
//
#include <hip/hip_runtime.h>
#include <hip/hip_bf16.h>
#include <math.h>

#define N_NODES   8192
#define NUM_E     49152
#define NUM_EDGES (NUM_E + N_NODES)   // 57344 (with self loops)
#define H_HEADS   6
#define C_DIM     512
#define HC        (H_HEADS * C_DIM)   // 3072
#define XLR       (2 * HC)            // 6144: xl | xr concatenated per row
#define N_FEAT    37
#define LRELU_SLOPE 0.2f
#define SELU_LAMBDA 1.0507009873554805f
#define SELU_ALPHA  1.6732632423543772f

typedef __bf16 bf16_t;
typedef bf16_t bf16x8 __attribute__((ext_vector_type(8)));
typedef float  f32x4  __attribute__((ext_vector_type(4)));
typedef float  f32x2  __attribute__((ext_vector_type(2)));

__device__ __forceinline__ int edge_src(const int* ei, int e) {
    return e < NUM_E ? ei[e] : (e - NUM_E);
}
__device__ __forceinline__ int edge_dst(const int* ei, int e) {
    return e < NUM_E ? ei[NUM_E + e] : (e - NUM_E);
}
__device__ __forceinline__ float selu_f(float v) {
    return v > 0.f ? SELU_LAMBDA * v : SELU_LAMBDA * SELU_ALPHA * (__expf(v) - 1.f);
}
__device__ __forceinline__ void gload_lds16(const void* g, void* l) {
    __builtin_amdgcn_global_load_lds((const __attribute__((address_space(1))) void*)g,
                                     (__attribute__((address_space(3))) void*)l, 16, 0, 0);
}

// ---------------- K1: hidden0 = selu([x[:,2:],lf,cf] @ W_lin + b) -> bf16, coord init
__global__ __launch_bounds__(512) void k_hidden0(
    const float* __restrict__ x, const float* __restrict__ lf,
    const float* __restrict__ cf, const float* __restrict__ W,
    const float* __restrict__ b, bf16_t* __restrict__ hidden,
    float* __restrict__ coord)
{
    int n = blockIdx.x;
    int c = threadIdx.x;
    __shared__ float f[N_FEAT];
    if (c < 5)            f[c] = x[n*7 + 2 + c];
    else if (c < 21)      f[c] = lf[n*16 + (c-5)];
    else if (c < N_FEAT)  f[c] = cf[n*16 + (c-21)];
    if (c < 2) coord[n*2 + c] = x[n*7 + c];
    __syncthreads();
    float acc = b[c];
    #pragma unroll
    for (int k = 0; k < N_FEAT; ++k) acc = fmaf(f[k], W[k*C_DIM + c], acc);
    hidden[n*C_DIM + c] = (bf16_t)selu_f(acc);
}

// ---------------- weight transpose+convert: W (514x3072 fp32, skip rows 0,1) -> WT (3072x512 bf16)
__global__ __launch_bounds__(256) void k_wt_transpose(const float* __restrict__ W,
                                                      bf16_t* __restrict__ WT)
{
    __shared__ float tile[32][33];
    int k0 = blockIdx.y * 32;
    int n0 = blockIdx.x * 32;
    int tx = threadIdx.x & 31, ty = threadIdx.x >> 5;
    #pragma unroll
    for (int i = 0; i < 4; ++i)
        tile[ty + i*8][tx] = W[(size_t)(k0 + 2 + ty + i*8) * HC + n0 + tx];
    __syncthreads();
    #pragma unroll
    for (int i = 0; i < 4; ++i)
        WT[(size_t)(n0 + ty + i*8) * C_DIM + k0 + tx] = (bf16_t)tile[tx][ty + i*8];
}

// ---------------- CSR build
__global__ void k_hist(const int* __restrict__ ei, int* __restrict__ counts) {
    int e = blockIdx.x * blockDim.x + threadIdx.x;
    if (e >= NUM_EDGES) return;
    atomicAdd(&counts[edge_dst(ei, e)], 1);
}

__global__ __launch_bounds__(256) void k_scan(const int* __restrict__ counts,
                                              int* __restrict__ row_ptr,
                                              int* __restrict__ cursor) {
    __shared__ int part[256];
    __shared__ int off[257];
    int t = threadIdx.x;
    int base = t * 32;
    int local[32];
    int s = 0;
    #pragma unroll
    for (int i = 0; i < 32; ++i) { local[i] = s; s += counts[base + i]; }
    part[t] = s;
    __syncthreads();
    if (t == 0) {
        off[0] = 0;
        for (int i = 0; i < 256; ++i) off[i+1] = off[i] + part[i];
    }
    __syncthreads();
    int o = off[t];
    #pragma unroll
    for (int i = 0; i < 32; ++i) {
        int v = o + local[i];
        row_ptr[base + i] = v;
        cursor[base + i]  = v;
    }
    if (t == 255) row_ptr[N_NODES] = off[256];
}

__global__ void k_scatter(const int* __restrict__ ei, int* __restrict__ cursor,
                          int* __restrict__ csr_eid) {
    int e = blockIdx.x * blockDim.x + threadIdx.x;
    if (e >= NUM_EDGES) return;
    int pos = atomicAdd(&cursor[edge_dst(ei, e)], 1);
    csr_eid[pos] = e;
}

// ---------------- bf16 MFMA GEMM: double-buffered LDS, staging issued BEFORE compute phase
// so the global_load_lds latency overlaps ds_read+MFMA; one barrier per K-iter.
// XOR-swizzled K-chunks keep ds_read_b128 conflict-free. (verified WIN, R7)
#define GM 128
#define GN 128
#define GK 32
__global__ __launch_bounds__(256) void k_gemm_bf16(
    const bf16_t* __restrict__ A,
    const bf16_t* __restrict__ BT,
    const float*  __restrict__ Wl,
    const float*  __restrict__ Wr,
    const float*  __restrict__ coord,
    bf16_t* __restrict__ out)
{
    __shared__ bf16_t As[2][GM][GK];   // 16 KB
    __shared__ bf16_t Bs[2][GM][GK];   // 16 KB
    int tid  = threadIdx.x;
    int wave = tid >> 6;
    int lane = tid & 63;
    int rowBase = blockIdx.y * GM;
    int colBase = blockIdx.x * GN;
    int wr = (wave >> 1) * 64;
    int wc = (wave & 1) * 64;

    f32x4 acc[4][4] = {};

    int gsw = (((lane & 3) ^ ((lane >> 3) & 3))) * 8;
    const bf16_t* Ag = A  + (size_t)(rowBase + wave*32 + (lane >> 2)) * C_DIM + gsw;
    const bf16_t* Bg = BT + (size_t)(colBase + wave*32 + (lane >> 2)) * C_DIM + gsw;
    int m16 = lane & 15;
    int q8s = (((lane >> 4) ^ ((lane >> 1) & 3))) * 8;

    gload_lds16(Ag,            &As[0][wave*32     ][0]);
    gload_lds16(Ag + 16*C_DIM, &As[0][wave*32 + 16][0]);
    gload_lds16(Bg,            &Bs[0][wave*32     ][0]);
    gload_lds16(Bg + 16*C_DIM, &Bs[0][wave*32 + 16][0]);

    int p = 0;
    for (int k0 = 0; k0 < C_DIM; k0 += GK) {
        __syncthreads();
        if (k0 + GK < C_DIM) {
            gload_lds16(Ag + k0 + GK,            &As[p^1][wave*32     ][0]);
            gload_lds16(Ag + k0 + GK + 16*C_DIM, &As[p^1][wave*32 + 16][0]);
            gload_lds16(Bg + k0 + GK,            &Bs[p^1][wave*32     ][0]);
            gload_lds16(Bg + k0 + GK + 16*C_DIM, &Bs[p^1][wave*32 + 16][0]);
        }
        bf16x8 af[4], bfr[4];
        #pragma unroll
        for (int i = 0; i < 4; ++i) af[i]  = *(const bf16x8*)&As[p][wr + i*16 + m16][q8s];
        #pragma unroll
        for (int j = 0; j < 4; ++j) bfr[j] = *(const bf16x8*)&Bs[p][wc + j*16 + m16][q8s];
        #pragma unroll
        for (int i = 0; i < 4; ++i)
            #pragma unroll
            for (int j = 0; j < 4; ++j)
                acc[i][j] = __builtin_amdgcn_mfma_f32_16x16x32_bf16(af[i], bfr[j], acc[i][j], 0, 0, 0);
        p ^= 1;
    }

    const float* Wtop = (colBase < HC) ? Wl : Wr;
    int coff = (colBase < HC) ? 0 : HC;

    int ccol  = lane & 15;
    int crow4 = (lane >> 4) * 4;
    #pragma unroll
    for (int i = 0; i < 4; ++i) {
        #pragma unroll
        for (int r = 0; r < 4; ++r) {
            int row = rowBase + wr + i*16 + crow4 + r;
            float c0 = coord[row*2 + 0], c1 = coord[row*2 + 1];
            size_t rb = (size_t)row * XLR;
            #pragma unroll
            for (int j = 0; j < 4; ++j) {
                int col = colBase + wc + j*16 + ccol;
                int wcol = col - coff;
                out[rb + col] = (bf16_t)(acc[i][j][r] + c0 * Wtop[wcol] + c1 * Wtop[HC + wcol]);
            }
        }
    }
}

// ---------------- fused attention, no-max softmax, 2-edge unroll (R6 form: VGPR 32,
// full occupancy — 4-edge unroll hits the vgpr=64 occupancy cliff, measured R7 LOSS)
#define MAX_DEG 128
__global__ __launch_bounds__(384) void k_attn_agg(
    const bf16_t* __restrict__ xlr,
    const int* __restrict__ row_ptr, const int* __restrict__ csr_eid,
    const int* __restrict__ ei, const float* __restrict__ att,
    const float* __restrict__ gat_bias, const float* __restrict__ W_coord,
    const float* __restrict__ b_coord, const float* __restrict__ coord_in,
    bf16_t* __restrict__ hidden, float* __restrict__ coord_out)
{
    int n = blockIdx.x;
    int tid = threadIdx.x;
    int h = tid >> 6, lane = tid & 63;
    __shared__ int   s_src[MAX_DEG];
    __shared__ float s_acc[HC];        // 12 KB
    __shared__ float s_red[12];

    int beg = row_ptr[n];
    int deg = min(row_ptr[n + 1] - beg, MAX_DEG);
    for (int j = tid; j < deg; j += 384) s_src[j] = edge_src(ei, csr_eid[beg + j]);
    __syncthreads();

    size_t off = (size_t)h * C_DIM + lane * 8;
    bf16x8 xrv = *(const bf16x8*)(xlr + (size_t)n * XLR + HC + off);
    f32x2 xr2[4], at2[4], ac2[4] = {};
    #pragma unroll
    for (int i = 0; i < 4; ++i) {
        xr2[i] = f32x2{(float)xrv[2*i], (float)xrv[2*i+1]};
        at2[i] = f32x2{att[off + 2*i], att[off + 2*i + 1]};
    }

    float l = 0.f;
    int j = 0;
    for (; j + 2 <= deg; j += 2) {
        bf16x8 xa = *(const bf16x8*)(xlr + (size_t)s_src[j]     * XLR + off);
        bf16x8 xb = *(const bf16x8*)(xlr + (size_t)s_src[j + 1] * XLR + off);
        f32x2 xla[4], xlb[4];
        #pragma unroll
        for (int i = 0; i < 4; ++i) {
            xla[i] = f32x2{(float)xa[2*i], (float)xa[2*i+1]};
            xlb[i] = f32x2{(float)xb[2*i], (float)xb[2*i+1]};
        }
        f32x2 sa = {0.f, 0.f}, sb = {0.f, 0.f};
        #pragma unroll
        for (int i = 0; i < 4; ++i) {
            f32x2 va = xla[i] + xr2[i];
            f32x2 vb = xlb[i] + xr2[i];
            sa += __builtin_elementwise_max(va, va * LRELU_SLOPE) * at2[i];
            sb += __builtin_elementwise_max(vb, vb * LRELU_SLOPE) * at2[i];
        }
        float suma = sa.x + sa.y, sumb = sb.x + sb.y;
        #pragma unroll
        for (int o = 1; o < 64; o <<= 1) {
            suma += __shfl_xor(suma, o);
            sumb += __shfl_xor(sumb, o);
        }
        float aa = __expf(suma), ab = __expf(sumb);
        l += aa + ab;
        #pragma unroll
        for (int i = 0; i < 4; ++i) ac2[i] += aa * xla[i] + ab * xlb[i];
    }
    if (j < deg) {
        bf16x8 xa = *(const bf16x8*)(xlr + (size_t)s_src[j] * XLR + off);
        f32x2 xla[4];
        #pragma unroll
        for (int i = 0; i < 4; ++i) xla[i] = f32x2{(float)xa[2*i], (float)xa[2*i+1]};
        f32x2 sa = {0.f, 0.f};
        #pragma unroll
        for (int i = 0; i < 4; ++i) {
            f32x2 va = xla[i] + xr2[i];
            sa += __builtin_elementwise_max(va, va * LRELU_SLOPE) * at2[i];
        }
        float suma = sa.x + sa.y;
        #pragma unroll
        for (int o = 1; o < 64; o <<= 1) suma += __shfl_xor(suma, o);
        float aa = __expf(suma);
        l += aa;
        #pragma unroll
        for (int i = 0; i < 4; ++i) ac2[i] += aa * xla[i];
    }

    float invl = 1.f / (l + 1e-16f) * (1.f / 6.f);   // fold head-mean
    #pragma unroll
    for (int i = 0; i < 4; ++i) {
        s_acc[off + 2*i]     = ac2[i].x * invl;
        s_acc[off + 2*i + 1] = ac2[i].y * invl;
    }
    __syncthreads();

    float p0 = 0.f, p1 = 0.f;
    for (int c = tid; c < C_DIM; c += 384) {
        float s = 0.f;
        #pragma unroll
        for (int hh = 0; hh < H_HEADS; ++hh) s += s_acc[hh * C_DIM + c];
        float hv = selu_f(s + gat_bias[c]);
        hidden[n * C_DIM + c] = (bf16_t)hv;
        p0 = fmaf(hv, W_coord[c * 2 + 0], p0);
        p1 = fmaf(hv, W_coord[c * 2 + 1], p1);
    }
    #pragma unroll
    for (int o = 32; o > 0; o >>= 1) { p0 += __shfl_down(p0, o); p1 += __shfl_down(p1, o); }
    if (lane == 0) { s_red[h * 2] = p0; s_red[h * 2 + 1] = p1; }
    __syncthreads();
    if (tid == 0) {
        float o0 = b_coord[0], o1 = b_coord[1];
        #pragma unroll
        for (int w = 0; w < H_HEADS; ++w) { o0 += s_red[w * 2]; o1 += s_red[w * 2 + 1]; }
        float cx = coord_in[n * 2 + 0], cy = coord_in[n * 2 + 1];
        float ox = (cx == 0.0f) ? 0.f : ((cx == 1.0f) ? 1.f : o0);
        float oy = (cy == 1.0f) ? 1.f : ((cy == 0.0f) ? 0.f : o1);
        coord_out[n * 2 + 0] = ox;
        coord_out[n * 2 + 1] = oy;
    }
}

extern "C" void kernel_launch(void* const* d_in, const int* in_sizes, int n_in,
                              void* d_out, int out_size, void* d_ws, size_t ws_size,
                              hipStream_t stream)
{
    const float* x       = (const float*)d_in[0];
    const float* lf      = (const float*)d_in[1];
    const float* cf      = (const float*)d_in[2];
    const float* W_lin   = (const float*)d_in[3];
    const float* b_lin   = (const float*)d_in[4];
    const float* Wl      = (const float*)d_in[5];
    const float* Wr      = (const float*)d_in[6];
    const float* att     = (const float*)d_in[7];
    const float* gbias   = (const float*)d_in[8];
    const float* W_coord = (const float*)d_in[9];
    const float* b_coord = (const float*)d_in[10];
    const int*   ei      = (const int*)d_in[11];

    char* w = (char*)d_ws;
    auto alloc = [&](size_t bytes) { char* p = w; w += (bytes + 255) & ~255ull; return p; };
    bf16_t*   hidden  = (bf16_t*)alloc((size_t)N_NODES * C_DIM * 2);
    bf16_t*   WT      = (bf16_t*)alloc((size_t)XLR * C_DIM * 2);
    bf16_t*   xlr     = (bf16_t*)alloc((size_t)N_NODES * XLR * 2);
    int*      counts  = (int*)alloc((size_t)N_NODES * 4);
    int*      row_ptr = (int*)alloc((size_t)(N_NODES + 1) * 4);
    int*      cursor  = (int*)alloc((size_t)N_NODES * 4);
    int*      csr_eid = (int*)alloc((size_t)NUM_EDGES * 4);
    float*    cA      = (float*)alloc((size_t)N_NODES * 2 * 4);
    float*    cB      = (float*)alloc((size_t)N_NODES * 2 * 4);

    hipMemsetAsync(counts, 0, (size_t)N_NODES * 4, stream);
    k_hidden0<<<N_NODES, 512, 0, stream>>>(x, lf, cf, W_lin, b_lin, hidden, cA);
    {
        dim3 tg(HC / 32, C_DIM / 32);
        k_wt_transpose<<<tg, 256, 0, stream>>>(Wl, WT);
        k_wt_transpose<<<tg, 256, 0, stream>>>(Wr, WT + (size_t)HC * C_DIM);
    }
    k_hist<<<(NUM_EDGES + 255) / 256, 256, 0, stream>>>(ei, counts);
    k_scan<<<1, 256, 0, stream>>>(counts, row_ptr, cursor);
    k_scatter<<<(NUM_EDGES + 255) / 256, 256, 0, stream>>>(ei, cursor, csr_eid);

    float* cin = cA;
    for (int it = 0; it < 3; ++it) {
        float* cout = (it == 2) ? (float*)d_out : ((it == 0) ? cB : cA);
        dim3 g(XLR / GN, N_NODES / GM);
        k_gemm_bf16<<<g, 256, 0, stream>>>(hidden, WT, Wl, Wr, cin, xlr);
        k_attn_agg<<<N_NODES, 384, 0, stream>>>(xlr, row_ptr, csr_eid, ei, att,
                                                gbias, W_coord, b_coord, cin, hidden, cout);
        cin = cout;
    }
}